// Round 6
// baseline (232.491 us; speedup 1.0000x reference)
//
#include <hip/hip_runtime.h>
#include <hip/hip_bf16.h>

#define NEG_SLOPE 0.2f
#define LN_EPS 1e-5f
#define D 64          // Din == Dout == 64
#define BSH 6         // 64 dst-nodes per bucket
#define BNODES 64
#define NBMAX 1024    // supports N <= 65536
#define BCAP 1792     // records per bucket (avg 1280 for N=50k,E=1M; +14 sigma)
#define OVFCAP 65536  // overflow list capacity (safety; normally 0 used)

typedef unsigned long long u64;

// ---------------------------------------------------------------------------
// Kernel 1: hW = h @ W^T   (N x 64), plus s1[i] = hW[i].a1, s2[i] = hW[i].a2
// One wave per node: lane j owns output column j.
// ---------------------------------------------------------------------------
__global__ void k_hw_scores(const float* __restrict__ h,
                            const float* __restrict__ W,
                            const float* __restrict__ a,
                            float* __restrict__ hW,
                            float* __restrict__ s1,
                            float* __restrict__ s2,
                            int N) {
    __shared__ float Wt[D * D];   // Wt[k][j] = W[j][k]
    __shared__ float a_sh[2 * D];

    for (int idx = threadIdx.x; idx < D * D; idx += blockDim.x) {
        int j = idx >> 6, k = idx & 63;
        Wt[k * D + j] = W[j * D + k];
    }
    if (threadIdx.x < 2 * D) a_sh[threadIdx.x] = a[threadIdx.x];
    __syncthreads();

    const int lane = threadIdx.x & 63;
    const int wid  = threadIdx.x >> 6;
    const int wavesPerBlock = blockDim.x >> 6;
    const int nWaves = gridDim.x * wavesPerBlock;

    for (int i = blockIdx.x * wavesPerBlock + wid; i < N; i += nWaves) {
        float hv = h[(size_t)i * D + lane];
        float acc = 0.f;
        #pragma unroll
        for (int k = 0; k < D; ++k) {
            float hk = __shfl(hv, k, 64);
            acc = fmaf(hk, Wt[k * D + lane], acc);
        }
        hW[(size_t)i * D + lane] = acc;

        float p1 = acc * a_sh[lane];
        float p2 = acc * a_sh[D + lane];
        #pragma unroll
        for (int off = 32; off > 0; off >>= 1) {
            p1 += __shfl_xor(p1, off, 64);
            p2 += __shfl_xor(p2, off, 64);
        }
        if (lane == 0) { s1[i] = p1; s2[i] = p2; }
    }
}

// ---------------------------------------------------------------------------
// Kernel 2: fused edge pass.
//  ex = exp(leaky_relu(s1[src]+s2[dst]))   [no max-subtract: softmax is
//  shift-invariant; clamp at 60 keeps exp finite]
//  denom[src] += ex  (atomic)
//  record {ex, dstlocal, src} appended to bucket region (dst>>6) with
//  per-block two-phase reservation -> block-contiguous runs.
//  TPB=1024/EPT=4: same 4096 edges/block (run-length preserved) but 16
//  waves/block -> ~48% occupancy (was 9.4% at 256/16 -> latency-bound).
// ---------------------------------------------------------------------------
__global__ void __launch_bounds__(1024)
k_bin_denom(const int* __restrict__ src,
            const int* __restrict__ dst,
            const float* __restrict__ s1,
            const float* __restrict__ s2,
            float* __restrict__ denom,
            int* __restrict__ cnt_g,      // [nb] bucket fill counters (zeroed)
            u64* __restrict__ recs,       // [nb * BCAP]
            u64* __restrict__ ovf_rec,    // [OVFCAP]
            int* __restrict__ ovf_dst,    // [OVFCAP]
            int* __restrict__ ovf_n,      // scalar (zeroed)
            int E, int nb) {
    const int TPB = 1024, EPT = 4;        // 4096 edges per block
    __shared__ int lcnt[NBMAX], lbase[NBMAX], lfill[NBMAX];

    const int chunk = blockIdx.x * (TPB * EPT);
    for (int i = threadIdx.x; i < nb; i += TPB) { lcnt[i] = 0; lfill[i] = 0; }
    __syncthreads();

    int sv[EPT], dv[EPT];
    const int e0 = chunk + threadIdx.x * EPT;
    if (e0 + EPT <= E) {
        int4 s4 = *(const int4*)(src + e0);
        int4 d4 = *(const int4*)(dst + e0);
        sv[0] = s4.x; sv[1] = s4.y; sv[2] = s4.z; sv[3] = s4.w;
        dv[0] = d4.x; dv[1] = d4.y; dv[2] = d4.z; dv[3] = d4.w;
    } else {
        #pragma unroll
        for (int j = 0; j < EPT; ++j) {
            int i = e0 + j;
            sv[j] = (i < E) ? src[i] : 0;
            dv[j] = (i < E) ? dst[i] : -1;
        }
    }

    #pragma unroll
    for (int j = 0; j < EPT; ++j)
        if (dv[j] >= 0) atomicAdd(&lcnt[dv[j] >> BSH], 1);
    __syncthreads();

    for (int b = threadIdx.x; b < nb; b += TPB) {
        int l = lcnt[b];
        if (l) lbase[b] = atomicAdd(&cnt_g[b], l);   // reserve contiguous run
    }
    __syncthreads();

    #pragma unroll
    for (int j = 0; j < EPT; ++j) {
        int d_ = dv[j];
        if (d_ < 0) continue;
        int s = sv[j];
        float x = s1[s] + s2[d_];
        float e = x > 0.f ? x : NEG_SLOPE * x;
        float ex = expf(fminf(e, 60.f));
        atomicAdd(&denom[s], ex);
        int b = d_ >> BSH;
        // pack: [ex:32][0:6][dstl:6][src:20]
        u64 rec = ((u64)__float_as_uint(ex) << 32)
                | (unsigned)s | ((unsigned)(d_ & (BNODES - 1)) << 20);
        int r = lbase[b] + atomicAdd(&lfill[b], 1);
        if (r < BCAP) {
            recs[(size_t)b * BCAP + r] = rec;
        } else {
            int o = atomicAdd(ovf_n, 1);
            if (o < OVFCAP) { ovf_rec[o] = rec; ovf_dst[o] = d_; }
        }
    }
}

// ---------------------------------------------------------------------------
// Kernel 3: one block (512 thr, 8 waves) per 64-node bucket.
// Stage records, fold att = ex/denom[src], group by local dst in LDS,
// then aggregate with 4-edges-per-wave float4 gathers, residual + LN.
// Lane layout in aggregation: g = lane>>4 (edge slot), li = lane&15 (col/4).
// ---------------------------------------------------------------------------
__global__ void __launch_bounds__(512)
k_bucket_agg(const u64* __restrict__ recs,
             const int* __restrict__ cnt_g,
             const float* __restrict__ denom,
             const float* __restrict__ hW,
             const float* __restrict__ gamma,
             const float* __restrict__ beta,
             const u64* __restrict__ ovf_rec,
             const int* __restrict__ ovf_dst,
             const int* __restrict__ ovf_n_p,
             float* __restrict__ out,
             int N) {
    __shared__ u64 ro[BCAP];
    __shared__ int hh[BNODES], oo[BNODES], cc[BNODES];

    const int b    = blockIdx.x;
    const int tid  = threadIdx.x;
    const int lane = tid & 63;
    const int wid  = tid >> 6;            // 8 waves
    const int g    = lane >> 4;           // edge-slot group 0..3
    const int li   = lane & 15;           // column quad 0..15
    const int node0 = b << BSH;
    const int nn    = min(BNODES, N - node0);
    const int total = min(cnt_g[b], BCAP);

    // ---- stage records (coalesced) + fold att ----
    u64 rr[4]; bool valid[4];
    const u64* base = recs + (size_t)b * BCAP;
    #pragma unroll
    for (int q = 0; q < 4; ++q) {
        int idx = tid + q * 512;
        valid[q] = idx < total;
        rr[q] = valid[q] ? base[idx] : 0;
    }
    if (tid < BNODES) hh[tid] = 0;
    __syncthreads();

    #pragma unroll
    for (int q = 0; q < 4; ++q) if (valid[q]) {
        int s = (unsigned)rr[q] & 0xFFFFF;
        float ex = __uint_as_float((unsigned)(rr[q] >> 32));
        float att = ex / denom[s];
        rr[q] = (rr[q] & 0xFFFFFFFFull) | ((u64)__float_as_uint(att) << 32);
        atomicAdd(&hh[((unsigned)rr[q] >> 20) & (BNODES - 1)], 1);
    }
    __syncthreads();

    // ---- exclusive scan over 64 counters ----
    if (tid < BNODES) oo[tid] = hh[tid];
    __syncthreads();
    for (int off = 1; off < BNODES; off <<= 1) {
        int t = 0;
        if (tid < BNODES && tid >= off) t = oo[tid - off];
        __syncthreads();
        if (tid < BNODES) oo[tid] += t;
        __syncthreads();
    }
    if (tid < BNODES) { int e_ = oo[tid] - hh[tid]; oo[tid] = e_; cc[tid] = e_; }
    __syncthreads();

    // ---- scatter into dst-grouped LDS buffer ----
    #pragma unroll
    for (int q = 0; q < 4; ++q) if (valid[q])
        ro[atomicAdd(&cc[((unsigned)rr[q] >> 20) & (BNODES - 1)], 1)] = rr[q];
    __syncthreads();

    int ovn = *ovf_n_p;
    if (ovn > OVFCAP) ovn = OVFCAP;

    // ---- aggregate + residual + LayerNorm; wave owns nodes [wid*8, wid*8+8) ----
    #pragma unroll
    for (int k = 0; k < 8; ++k) {
        int nl = (wid << 3) + k;
        if (nl >= nn) break;
        int beg = oo[nl], end = cc[nl];

        float ax = 0.f, ay = 0.f, az = 0.f, aw = 0.f;
        for (int p = beg; p < end; p += 4) {
            int idx = p + g;
            float att = 0.f; int s = 0;
            if (idx < end) {
                u64 r2 = ro[idx];
                s = (unsigned)r2 & 0xFFFFF;
                att = __uint_as_float((unsigned)(r2 >> 32));
            }
            const float4 v = *(const float4*)(hW + (size_t)s * D + li * 4);
            ax = fmaf(att, v.x, ax); ay = fmaf(att, v.y, ay);
            az = fmaf(att, v.z, az); aw = fmaf(att, v.w, aw);
        }

        // overflow safety path (normally ovn == 0); add on group 0 only
        for (int r = 0; r < ovn; ++r) {
            if (ovf_dst[r] != node0 + nl) continue;
            if (g == 0) {
                u64 r2 = ovf_rec[r];
                int s = (unsigned)r2 & 0xFFFFF;
                float ex = __uint_as_float((unsigned)(r2 >> 32));
                float att = ex / denom[s];
                const float4 v = *(const float4*)(hW + (size_t)s * D + li * 4);
                ax = fmaf(att, v.x, ax); ay = fmaf(att, v.y, ay);
                az = fmaf(att, v.z, az); aw = fmaf(att, v.w, aw);
            }
        }

        // reduce across the 4 edge-slot groups
        ax += __shfl_xor(ax, 16, 64); ax += __shfl_xor(ax, 32, 64);
        ay += __shfl_xor(ay, 16, 64); ay += __shfl_xor(ay, 32, 64);
        az += __shfl_xor(az, 16, 64); az += __shfl_xor(az, 32, 64);
        aw += __shfl_xor(aw, 16, 64); aw += __shfl_xor(aw, 32, 64);

        // residual
        const float4 hv = *(const float4*)(hW + (size_t)(node0 + nl) * D + li * 4);
        float x0 = hv.x + ax, x1 = hv.y + ay, x2 = hv.z + az, x3 = hv.w + aw;

        // LayerNorm over 64 cols (16-lane groups hold replicated data)
        float sm = x0 + x1 + x2 + x3;
        sm += __shfl_xor(sm, 1, 64); sm += __shfl_xor(sm, 2, 64);
        sm += __shfl_xor(sm, 4, 64); sm += __shfl_xor(sm, 8, 64);
        float mu = sm * (1.f / D);
        float d0 = x0 - mu, d1 = x1 - mu, d2 = x2 - mu, d3 = x3 - mu;
        float vv = d0 * d0 + d1 * d1 + d2 * d2 + d3 * d3;
        vv += __shfl_xor(vv, 1, 64); vv += __shfl_xor(vv, 2, 64);
        vv += __shfl_xor(vv, 4, 64); vv += __shfl_xor(vv, 8, 64);
        float inv = rsqrtf(vv * (1.f / D) + LN_EPS);

        if (g == 0) {
            const float4 gm = *(const float4*)(gamma + li * 4);
            const float4 bt = *(const float4*)(beta + li * 4);
            float4 o;
            o.x = d0 * inv * gm.x + bt.x;
            o.y = d1 * inv * gm.y + bt.y;
            o.z = d2 * inv * gm.z + bt.z;
            o.w = d3 * inv * gm.w + bt.w;
            *(float4*)(out + (size_t)(node0 + nl) * D + li * 4) = o;
        }
    }
}

// ---------------------------------------------------------------------------
static inline size_t align256(size_t x) { return (x + 255) & ~size_t(255); }

extern "C" void kernel_launch(void* const* d_in, const int* in_sizes, int n_in,
                              void* d_out, int out_size, void* d_ws, size_t ws_size,
                              hipStream_t stream) {
    const float* h    = (const float*)d_in[0];
    const int*   ei   = (const int*)d_in[1];
    const float* W    = (const float*)d_in[2];
    const float* a    = (const float*)d_in[3];
    const float* lng  = (const float*)d_in[4];
    const float* lnb  = (const float*)d_in[5];
    float* out = (float*)d_out;

    const int N = in_sizes[0] / D;
    const int E = in_sizes[1] / 2;
    const int* src = ei;        // edge_index[0]
    const int* dst = ei + E;    // edge_index[1]
    const int nb = (N + BNODES - 1) >> BSH;   // 64-node buckets (<= NBMAX)

    // workspace layout
    char* ws = (char*)d_ws;
    size_t off = 0;
    float* hW      = (float*)(ws + off); off += align256(sizeof(float) * (size_t)N * D);
    float* s1      = (float*)(ws + off); off += align256(sizeof(float) * (size_t)N);
    float* s2      = (float*)(ws + off); off += align256(sizeof(float) * (size_t)N);
    u64*   recs    = (u64*)  (ws + off); off += align256(sizeof(u64) * (size_t)nb * BCAP);
    u64*   ovf_rec = (u64*)  (ws + off); off += align256(sizeof(u64) * (size_t)OVFCAP);
    int*   ovf_dst = (int*)  (ws + off); off += align256(sizeof(int) * (size_t)OVFCAP);
    // zero-initialized tail: denom, cnt_g, ovf_n (contiguous -> one memset)
    size_t zero_off = off;
    float* denom   = (float*)(ws + off); off += align256(sizeof(float) * (size_t)N);
    int*   cnt_g   = (int*)  (ws + off); off += align256(sizeof(int) * (size_t)NBMAX);
    int*   ovf_n   = (int*)  (ws + off); off += align256(sizeof(int));
    size_t zero_bytes = off - zero_off;

    hipMemsetAsync(ws + zero_off, 0, zero_bytes, stream);

    // K1: hW + attention scores
    k_hw_scores<<<dim3(1024), dim3(256), 0, stream>>>(h, W, a, hW, s1, s2, N);

    // K2: fused exp + denom + bucket binning (4096 edges/block, 16 waves/block)
    k_bin_denom<<<dim3((E + 4095) / 4096), dim3(1024), 0, stream>>>(
        src, dst, s1, s2, denom, cnt_g, recs, ovf_rec, ovf_dst, ovf_n, E, nb);

    // K3: fused bucket sort + aggregate + residual + LayerNorm
    k_bucket_agg<<<dim3(nb), dim3(512), 0, stream>>>(
        recs, cnt_g, denom, hW, lng, lnb, ovf_rec, ovf_dst, ovf_n, out, N);
}

// Round 7
// 195.418 us; speedup vs baseline: 1.1897x; 1.1897x over previous
//
#include <hip/hip_runtime.h>
#include <hip/hip_bf16.h>

#define NEG_SLOPE 0.2f
#define LN_EPS 1e-5f
#define D 64          // Din == Dout == 64
// NOTE: u32 record packing {src:16|dst:16} requires N <= 65536 (problem: N=50000)
#define BSH 7         // 128 dst-nodes per bucket
#define BNODES 128
#define NBMAX 512     // dst-buckets (N <= 65536)
#define BCAP 3072     // records per dst-bucket (avg 2558; +10 sigma)
#define SSH 8         // 256 srcs per src-bucket
#define NSBMAX 256    // src-buckets (N <= 65536)
#define SCAP 6144     // records per src-bucket (avg 5102; +14 sigma)
#define OVFCAP 65536  // overflow list capacity (safety; normally 0 used)

typedef unsigned long long u64;
typedef unsigned int u32;

// ---------------------------------------------------------------------------
// Kernel 1: hW = h @ W^T   (N x 64), plus s1[i] = hW[i].a1, s2[i] = hW[i].a2
// ---------------------------------------------------------------------------
__global__ void k_hw_scores(const float* __restrict__ h,
                            const float* __restrict__ W,
                            const float* __restrict__ a,
                            float* __restrict__ hW,
                            float* __restrict__ s1,
                            float* __restrict__ s2,
                            int N) {
    __shared__ float Wt[D * D];   // Wt[k][j] = W[j][k]
    __shared__ float a_sh[2 * D];

    for (int idx = threadIdx.x; idx < D * D; idx += blockDim.x) {
        int j = idx >> 6, k = idx & 63;
        Wt[k * D + j] = W[j * D + k];
    }
    if (threadIdx.x < 2 * D) a_sh[threadIdx.x] = a[threadIdx.x];
    __syncthreads();

    const int lane = threadIdx.x & 63;
    const int wid  = threadIdx.x >> 6;
    const int wavesPerBlock = blockDim.x >> 6;
    const int nWaves = gridDim.x * wavesPerBlock;

    for (int i = blockIdx.x * wavesPerBlock + wid; i < N; i += nWaves) {
        float hv = h[(size_t)i * D + lane];
        float acc = 0.f;
        #pragma unroll
        for (int k = 0; k < D; ++k) {
            float hk = __shfl(hv, k, 64);
            acc = fmaf(hk, Wt[k * D + lane], acc);
        }
        hW[(size_t)i * D + lane] = acc;

        float p1 = acc * a_sh[lane];
        float p2 = acc * a_sh[D + lane];
        #pragma unroll
        for (int off = 32; off > 0; off >>= 1) {
            p1 += __shfl_xor(p1, off, 64);
            p2 += __shfl_xor(p2, off, 64);
        }
        if (lane == 0) { s1[i] = p1; s2[i] = p2; }
    }
}

__device__ __forceinline__ float edge_ex(float v1, float v2) {
    float x = v1 + v2;
    float e = x > 0.f ? x : NEG_SLOPE * x;
    return expf(fminf(e, 60.f));   // softmax shift-invariant; clamp for safety
}

// ---------------------------------------------------------------------------
// Kernel 2: edge pass, dual binning. No fp atomics, 4B records.
//  dst-copy: {src:16 | dstl:7}<<16? -> rec = src | (dstl<<16), bucket d>>7
//  src-copy: rec = src | (dst<<16), bucket s>>8  (for denom reduction)
// Per-block two-phase reservation -> block-contiguous runs.
// ---------------------------------------------------------------------------
__global__ void __launch_bounds__(1024)
k_bin(const int* __restrict__ src,
      const int* __restrict__ dst,
      const float* __restrict__ s1,
      const float* __restrict__ s2,
      float* __restrict__ denom,       // only overflow path writes (atomic)
      int* __restrict__ dcnt_g,        // [NBMAX]  (zeroed)
      u32* __restrict__ drecs,         // [nb * BCAP]
      int* __restrict__ scnt_g,        // [NSBMAX] (zeroed)
      u32* __restrict__ srecs,         // [nsb * SCAP]
      u32* __restrict__ ovf_rec,       // [OVFCAP]
      int* __restrict__ ovf_dst,       // [OVFCAP]
      int* __restrict__ ovf_n,         // scalar (zeroed)
      int E, int nb, int nsb) {
    const int TPB = 1024, EPT = 4;     // 4096 edges per block
    __shared__ int lcnt[NBMAX], lbase[NBMAX], lfill[NBMAX];
    __shared__ int scnt[NSBMAX], sbase[NSBMAX], sfill[NSBMAX];

    const int chunk = blockIdx.x * (TPB * EPT);
    for (int i = threadIdx.x; i < nb; i += TPB)  { lcnt[i] = 0; lfill[i] = 0; }
    for (int i = threadIdx.x; i < nsb; i += TPB) { scnt[i] = 0; sfill[i] = 0; }
    __syncthreads();

    int sv[EPT], dv[EPT];
    const int e0 = chunk + threadIdx.x * EPT;
    if (e0 + EPT <= E) {
        int4 s4 = *(const int4*)(src + e0);
        int4 d4 = *(const int4*)(dst + e0);
        sv[0] = s4.x; sv[1] = s4.y; sv[2] = s4.z; sv[3] = s4.w;
        dv[0] = d4.x; dv[1] = d4.y; dv[2] = d4.z; dv[3] = d4.w;
    } else {
        #pragma unroll
        for (int j = 0; j < EPT; ++j) {
            int i = e0 + j;
            sv[j] = (i < E) ? src[i] : 0;
            dv[j] = (i < E) ? dst[i] : -1;
        }
    }

    #pragma unroll
    for (int j = 0; j < EPT; ++j) {
        if (dv[j] >= 0) {
            atomicAdd(&lcnt[dv[j] >> BSH], 1);
            atomicAdd(&scnt[sv[j] >> SSH], 1);
        }
    }
    __syncthreads();

    for (int b = threadIdx.x; b < nb; b += TPB) {
        int l = lcnt[b];
        if (l) lbase[b] = atomicAdd(&dcnt_g[b], l);
    }
    for (int b = threadIdx.x; b < nsb; b += TPB) {
        int l = scnt[b];
        if (l) sbase[b] = atomicAdd(&scnt_g[b], l);
    }
    __syncthreads();

    #pragma unroll
    for (int j = 0; j < EPT; ++j) {
        int d_ = dv[j];
        if (d_ < 0) continue;
        int s = sv[j];

        // dst-binned record (for aggregation)
        int b = d_ >> BSH;
        u32 drec = (u32)s | ((u32)(d_ & (BNODES - 1)) << 16);
        int r = lbase[b] + atomicAdd(&lfill[b], 1);
        if (r < BCAP) {
            drecs[(size_t)b * BCAP + r] = drec;
        } else {
            int o = atomicAdd(ovf_n, 1);
            if (o < OVFCAP) { ovf_rec[o] = drec; ovf_dst[o] = d_; }
        }

        // src-binned record (for denom)
        int sb = s >> SSH;
        u32 srec = (u32)s | ((u32)d_ << 16);
        int rs = sbase[sb] + atomicAdd(&sfill[sb], 1);
        if (rs < SCAP) {
            srecs[(size_t)sb * SCAP + rs] = srec;
        } else {
            // rare fallback: contribute to denom directly
            atomicAdd(&denom[s], edge_ex(s1[s], s2[d_]));
        }
    }
}

// ---------------------------------------------------------------------------
// Kernel 2b: denom reduction. One block per src-bucket (256 srcs).
// LDS fp32 accumulation -> single contiguous global write (+= picks up
// any overflow-path atomic contributions from k_bin, which ran earlier).
// ---------------------------------------------------------------------------
__global__ void __launch_bounds__(512)
k_denom(const u32* __restrict__ srecs,
        const int* __restrict__ scnt_g,
        const float* __restrict__ s1,
        const float* __restrict__ s2,
        float* __restrict__ denom,
        int N) {
    __shared__ float acc[256];
    const int b = blockIdx.x;
    const int tid = threadIdx.x;
    if (tid < 256) acc[tid] = 0.f;
    __syncthreads();

    const int total = min(scnt_g[b], SCAP);
    const u32* base = srecs + (size_t)b * SCAP;
    for (int i = tid; i < total; i += 512) {
        u32 r = base[i];
        int s = r & 0xFFFF;
        int d = r >> 16;
        atomicAdd(&acc[s & 255], edge_ex(s1[s], s2[d]));
    }
    __syncthreads();

    if (tid < 256) {
        int g = (b << SSH) + tid;
        if (g < N) denom[g] += acc[tid];
    }
}

// ---------------------------------------------------------------------------
// Kernel 3: one block (1024 thr, 16 waves) per 128-node dst-bucket.
// Stage u32 records, recompute ex (s2 in LDS, s1/denom L2 gathers),
// group by local dst in LDS, aggregate with 4-edges-per-wave float4
// gathers, residual + LN.  g = lane>>4 (edge slot), li = lane&15 (col/4).
// ---------------------------------------------------------------------------
__global__ void __launch_bounds__(1024)
k_bucket_agg(const u32* __restrict__ drecs,
             const int* __restrict__ dcnt_g,
             const float* __restrict__ s1,
             const float* __restrict__ s2,
             const float* __restrict__ denom,
             const float* __restrict__ hW,
             const float* __restrict__ gamma,
             const float* __restrict__ beta,
             const u32* __restrict__ ovf_rec,
             const int* __restrict__ ovf_dst,
             const int* __restrict__ ovf_n_p,
             float* __restrict__ out,
             int N) {
    __shared__ u64 ro[BCAP];          // {att_bits:32 | rec:32}
    __shared__ float s2l[BNODES];
    __shared__ int hh[BNODES], oo[BNODES], cc[BNODES];

    const int b    = blockIdx.x;
    const int tid  = threadIdx.x;
    const int lane = tid & 63;
    const int wid  = tid >> 6;        // 16 waves
    const int g    = lane >> 4;       // edge-slot group 0..3
    const int li   = lane & 15;       // column quad 0..15
    const int node0 = b << BSH;
    const int nn    = min(BNODES, N - node0);
    const int total = min(dcnt_g[b], BCAP);

    if (tid < nn) s2l[tid] = s2[node0 + tid];
    if (tid < BNODES) hh[tid] = 0;
    __syncthreads();

    // ---- stage + compute att ----
    u64 rr[3]; bool valid[3];
    const u32* base = drecs + (size_t)b * BCAP;
    #pragma unroll
    for (int q = 0; q < 3; ++q) {
        int idx = tid + q * 1024;
        valid[q] = idx < total;
        u32 r = valid[q] ? base[idx] : 0u;
        if (valid[q]) {
            int s  = r & 0xFFFF;
            int dl = (r >> 16) & (BNODES - 1);
            float att = edge_ex(s1[s], s2l[dl]) / denom[s];
            rr[q] = ((u64)__float_as_uint(att) << 32) | (u64)r;
            atomicAdd(&hh[dl], 1);
        } else rr[q] = 0;
    }
    __syncthreads();

    // ---- exclusive scan over 128 counters ----
    if (tid < BNODES) oo[tid] = hh[tid];
    __syncthreads();
    for (int off = 1; off < BNODES; off <<= 1) {
        int t = 0;
        if (tid < BNODES && tid >= off) t = oo[tid - off];
        __syncthreads();
        if (tid < BNODES) oo[tid] += t;
        __syncthreads();
    }
    if (tid < BNODES) { int e_ = oo[tid] - hh[tid]; oo[tid] = e_; cc[tid] = e_; }
    __syncthreads();

    // ---- scatter into dst-grouped LDS buffer ----
    #pragma unroll
    for (int q = 0; q < 3; ++q) if (valid[q])
        ro[atomicAdd(&cc[((u32)rr[q] >> 16) & (BNODES - 1)], 1)] = rr[q];
    __syncthreads();

    int ovn = *ovf_n_p;
    if (ovn > OVFCAP) ovn = OVFCAP;

    // ---- aggregate + residual + LayerNorm; wave owns nodes wid*8..wid*8+7 ----
    #pragma unroll
    for (int k = 0; k < 8; ++k) {
        int nl = (wid << 3) + k;
        if (nl >= nn) break;
        int beg = oo[nl], end = cc[nl];

        float ax = 0.f, ay = 0.f, az = 0.f, aw = 0.f;
        for (int p = beg; p < end; p += 4) {
            int idx = p + g;
            float att = 0.f; int s = 0;
            if (idx < end) {
                u64 r2 = ro[idx];
                s = (u32)r2 & 0xFFFF;
                att = __uint_as_float((u32)(r2 >> 32));
            }
            const float4 v = *(const float4*)(hW + (size_t)s * D + li * 4);
            ax = fmaf(att, v.x, ax); ay = fmaf(att, v.y, ay);
            az = fmaf(att, v.z, az); aw = fmaf(att, v.w, aw);
        }

        // overflow safety path (normally ovn == 0); add on group 0 only
        for (int r = 0; r < ovn; ++r) {
            if (ovf_dst[r] != node0 + nl) continue;
            if (g == 0) {
                u32 r2 = ovf_rec[r];
                int s = r2 & 0xFFFF;
                float att = edge_ex(s1[s], s2l[nl]) / denom[s];
                const float4 v = *(const float4*)(hW + (size_t)s * D + li * 4);
                ax = fmaf(att, v.x, ax); ay = fmaf(att, v.y, ay);
                az = fmaf(att, v.z, az); aw = fmaf(att, v.w, aw);
            }
        }

        // reduce across the 4 edge-slot groups
        ax += __shfl_xor(ax, 16, 64); ax += __shfl_xor(ax, 32, 64);
        ay += __shfl_xor(ay, 16, 64); ay += __shfl_xor(ay, 32, 64);
        az += __shfl_xor(az, 16, 64); az += __shfl_xor(az, 32, 64);
        aw += __shfl_xor(aw, 16, 64); aw += __shfl_xor(aw, 32, 64);

        // residual
        const float4 hv = *(const float4*)(hW + (size_t)(node0 + nl) * D + li * 4);
        float x0 = hv.x + ax, x1 = hv.y + ay, x2 = hv.z + az, x3 = hv.w + aw;

        // LayerNorm over 64 cols
        float sm = x0 + x1 + x2 + x3;
        sm += __shfl_xor(sm, 1, 64); sm += __shfl_xor(sm, 2, 64);
        sm += __shfl_xor(sm, 4, 64); sm += __shfl_xor(sm, 8, 64);
        float mu = sm * (1.f / D);
        float d0 = x0 - mu, d1 = x1 - mu, d2 = x2 - mu, d3 = x3 - mu;
        float vv = d0 * d0 + d1 * d1 + d2 * d2 + d3 * d3;
        vv += __shfl_xor(vv, 1, 64); vv += __shfl_xor(vv, 2, 64);
        vv += __shfl_xor(vv, 4, 64); vv += __shfl_xor(vv, 8, 64);
        float inv = rsqrtf(vv * (1.f / D) + LN_EPS);

        if (g == 0) {
            const float4 gm = *(const float4*)(gamma + li * 4);
            const float4 bt = *(const float4*)(beta + li * 4);
            float4 o;
            o.x = d0 * inv * gm.x + bt.x;
            o.y = d1 * inv * gm.y + bt.y;
            o.z = d2 * inv * gm.z + bt.z;
            o.w = d3 * inv * gm.w + bt.w;
            *(float4*)(out + (size_t)(node0 + nl) * D + li * 4) = o;
        }
    }
}

// ---------------------------------------------------------------------------
static inline size_t align256(size_t x) { return (x + 255) & ~size_t(255); }

extern "C" void kernel_launch(void* const* d_in, const int* in_sizes, int n_in,
                              void* d_out, int out_size, void* d_ws, size_t ws_size,
                              hipStream_t stream) {
    const float* h    = (const float*)d_in[0];
    const int*   ei   = (const int*)d_in[1];
    const float* W    = (const float*)d_in[2];
    const float* a    = (const float*)d_in[3];
    const float* lng  = (const float*)d_in[4];
    const float* lnb  = (const float*)d_in[5];
    float* out = (float*)d_out;

    const int N = in_sizes[0] / D;
    const int E = in_sizes[1] / 2;
    const int* src = ei;        // edge_index[0]
    const int* dst = ei + E;    // edge_index[1]
    const int nb  = (N + BNODES - 1) >> BSH;   // dst-buckets
    const int nsb = (N + 255) >> SSH;          // src-buckets

    // workspace layout
    char* ws = (char*)d_ws;
    size_t off = 0;
    float* hW      = (float*)(ws + off); off += align256(sizeof(float) * (size_t)N * D);
    float* s1      = (float*)(ws + off); off += align256(sizeof(float) * (size_t)N);
    float* s2      = (float*)(ws + off); off += align256(sizeof(float) * (size_t)N);
    u32*   drecs   = (u32*)  (ws + off); off += align256(sizeof(u32) * (size_t)nb * BCAP);
    u32*   srecs   = (u32*)  (ws + off); off += align256(sizeof(u32) * (size_t)nsb * SCAP);
    u32*   ovf_rec = (u32*)  (ws + off); off += align256(sizeof(u32) * (size_t)OVFCAP);
    int*   ovf_dst = (int*)  (ws + off); off += align256(sizeof(int) * (size_t)OVFCAP);
    // zero-initialized tail: denom, dcnt_g, scnt_g, ovf_n (one memset)
    size_t zero_off = off;
    float* denom   = (float*)(ws + off); off += align256(sizeof(float) * (size_t)N);
    int*   dcnt_g  = (int*)  (ws + off); off += align256(sizeof(int) * (size_t)NBMAX);
    int*   scnt_g  = (int*)  (ws + off); off += align256(sizeof(int) * (size_t)NSBMAX);
    int*   ovf_n   = (int*)  (ws + off); off += align256(sizeof(int));
    size_t zero_bytes = off - zero_off;

    hipMemsetAsync(ws + zero_off, 0, zero_bytes, stream);

    // K1: hW + attention scores
    k_hw_scores<<<dim3(1024), dim3(256), 0, stream>>>(h, W, a, hW, s1, s2, N);

    // K2: dual binning (4096 edges/block), no fp atomics
    k_bin<<<dim3((E + 4095) / 4096), dim3(1024), 0, stream>>>(
        src, dst, s1, s2, denom, dcnt_g, drecs, scnt_g, srecs,
        ovf_rec, ovf_dst, ovf_n, E, nb, nsb);

    // K2b: denom reduction per src-bucket
    k_denom<<<dim3(nsb), dim3(512), 0, stream>>>(srecs, scnt_g, s1, s2, denom, N);

    // K3: fused bucket sort + aggregate + residual + LayerNorm
    k_bucket_agg<<<dim3(nb), dim3(1024), 0, stream>>>(
        drecs, dcnt_g, s1, s2, denom, hW, lng, lnb,
        ovf_rec, ovf_dst, ovf_n, out, N);
}

// Round 8
// 166.526 us; speedup vs baseline: 1.3961x; 1.1735x over previous
//
#include <hip/hip_runtime.h>
#include <hip/hip_bf16.h>

#define NEG_SLOPE 0.2f
#define LN_EPS 1e-5f
#define D 64          // Din == Dout == 64
// NOTE: u32 record packing {src:16|dst:16} requires N <= 65536 (problem: N=50000)
#define BSH 7         // 128 dst-nodes per bucket
#define BNODES 128
#define NBMAX 512     // dst-buckets (N <= 65536)
#define BCAP 3072     // records per dst-bucket (avg 2558; +10 sigma)
#define SSH 8         // 256 srcs per src-bucket
#define NSBMAX 256    // src-buckets (N <= 65536)
#define SCAP 6144     // records per src-bucket (avg 5102; +14 sigma)
#define OVFCAP 65536  // overflow list capacity (safety; normally 0 used)

typedef unsigned long long u64;
typedef unsigned int u32;

// ---------------------------------------------------------------------------
// Kernel 1: hW = h @ W^T   (N x 64), plus s1[i] = hW[i].a1, s2[i] = hW[i].a2
// Lane j holds W row j (= column j of W^T) in 64 VGPRs; node index is
// readfirstlane'd so h-row loads are wave-uniform (scalar/SMEM pipe);
// inner loop is 64 pure FMAs on 4 independent accumulator chains.
// ---------------------------------------------------------------------------
__global__ void __launch_bounds__(256, 4)
k_hw_scores(const float* __restrict__ h,
            const float* __restrict__ W,
            const float* __restrict__ a,
            float* __restrict__ hW,
            float* __restrict__ s1,
            float* __restrict__ s2,
            int N) {
    const int lane = threadIdx.x & 63;
    const int wid  = threadIdx.x >> 6;
    const int wavesPerBlock = blockDim.x >> 6;
    const int nWaves = gridDim.x * wavesPerBlock;

    // W row for this lane -> registers (16 KB total, L1/L2-served, once/wave)
    float wcol[D];
    {
        const float4* wr = (const float4*)(W + (size_t)lane * D);
        #pragma unroll
        for (int q = 0; q < D / 4; ++q) {
            float4 w4 = wr[q];
            wcol[q * 4 + 0] = w4.x; wcol[q * 4 + 1] = w4.y;
            wcol[q * 4 + 2] = w4.z; wcol[q * 4 + 3] = w4.w;
        }
    }
    const float a1l = a[lane];
    const float a2l = a[D + lane];

    for (int i = blockIdx.x * wavesPerBlock + wid; i < N; i += nWaves) {
        const int iu = __builtin_amdgcn_readfirstlane(i);
        const float* hr = h + (size_t)iu * D;   // wave-uniform -> scalar loads

        float acc0 = 0.f, acc1 = 0.f, acc2 = 0.f, acc3 = 0.f;
        #pragma unroll
        for (int k = 0; k < D; k += 4) {
            acc0 = fmaf(hr[k + 0], wcol[k + 0], acc0);
            acc1 = fmaf(hr[k + 1], wcol[k + 1], acc1);
            acc2 = fmaf(hr[k + 2], wcol[k + 2], acc2);
            acc3 = fmaf(hr[k + 3], wcol[k + 3], acc3);
        }
        float c = (acc0 + acc1) + (acc2 + acc3);
        hW[(size_t)iu * D + lane] = c;

        float p1 = c * a1l;
        float p2 = c * a2l;
        #pragma unroll
        for (int off = 32; off > 0; off >>= 1) {
            p1 += __shfl_xor(p1, off, 64);
            p2 += __shfl_xor(p2, off, 64);
        }
        if (lane == 0) { s1[iu] = p1; s2[iu] = p2; }
    }
}

__device__ __forceinline__ float edge_ex(float v1, float v2) {
    float x = v1 + v2;
    float e = x > 0.f ? x : NEG_SLOPE * x;
    return expf(fminf(e, 60.f));   // softmax shift-invariant; clamp for safety
}

// ---------------------------------------------------------------------------
// Kernel 2: edge pass, dual binning. No fp atomics, 4B records.
//  dst-copy: rec = src | (dstl<<16), bucket d>>7
//  src-copy: rec = src | (dst<<16),  bucket s>>8  (for denom reduction)
// Per-block two-phase reservation -> block-contiguous runs.
// ---------------------------------------------------------------------------
__global__ void __launch_bounds__(1024)
k_bin(const int* __restrict__ src,
      const int* __restrict__ dst,
      const float* __restrict__ s1,
      const float* __restrict__ s2,
      float* __restrict__ denom,       // only overflow path writes (atomic)
      int* __restrict__ dcnt_g,        // [NBMAX]  (zeroed)
      u32* __restrict__ drecs,         // [nb * BCAP]
      int* __restrict__ scnt_g,        // [NSBMAX] (zeroed)
      u32* __restrict__ srecs,         // [nsb * SCAP]
      u32* __restrict__ ovf_rec,       // [OVFCAP]
      int* __restrict__ ovf_dst,       // [OVFCAP]
      int* __restrict__ ovf_n,         // scalar (zeroed)
      int E, int nb, int nsb) {
    const int TPB = 1024, EPT = 4;     // 4096 edges per block
    __shared__ int lcnt[NBMAX], lbase[NBMAX], lfill[NBMAX];
    __shared__ int scnt[NSBMAX], sbase[NSBMAX], sfill[NSBMAX];

    const int chunk = blockIdx.x * (TPB * EPT);
    for (int i = threadIdx.x; i < nb; i += TPB)  { lcnt[i] = 0; lfill[i] = 0; }
    for (int i = threadIdx.x; i < nsb; i += TPB) { scnt[i] = 0; sfill[i] = 0; }
    __syncthreads();

    int sv[EPT], dv[EPT];
    const int e0 = chunk + threadIdx.x * EPT;
    if (e0 + EPT <= E) {
        int4 s4 = *(const int4*)(src + e0);
        int4 d4 = *(const int4*)(dst + e0);
        sv[0] = s4.x; sv[1] = s4.y; sv[2] = s4.z; sv[3] = s4.w;
        dv[0] = d4.x; dv[1] = d4.y; dv[2] = d4.z; dv[3] = d4.w;
    } else {
        #pragma unroll
        for (int j = 0; j < EPT; ++j) {
            int i = e0 + j;
            sv[j] = (i < E) ? src[i] : 0;
            dv[j] = (i < E) ? dst[i] : -1;
        }
    }

    #pragma unroll
    for (int j = 0; j < EPT; ++j) {
        if (dv[j] >= 0) {
            atomicAdd(&lcnt[dv[j] >> BSH], 1);
            atomicAdd(&scnt[sv[j] >> SSH], 1);
        }
    }
    __syncthreads();

    for (int b = threadIdx.x; b < nb; b += TPB) {
        int l = lcnt[b];
        if (l) lbase[b] = atomicAdd(&dcnt_g[b], l);
    }
    for (int b = threadIdx.x; b < nsb; b += TPB) {
        int l = scnt[b];
        if (l) sbase[b] = atomicAdd(&scnt_g[b], l);
    }
    __syncthreads();

    #pragma unroll
    for (int j = 0; j < EPT; ++j) {
        int d_ = dv[j];
        if (d_ < 0) continue;
        int s = sv[j];

        // dst-binned record (for aggregation)
        int b = d_ >> BSH;
        u32 drec = (u32)s | ((u32)(d_ & (BNODES - 1)) << 16);
        int r = lbase[b] + atomicAdd(&lfill[b], 1);
        if (r < BCAP) {
            drecs[(size_t)b * BCAP + r] = drec;
        } else {
            int o = atomicAdd(ovf_n, 1);
            if (o < OVFCAP) { ovf_rec[o] = drec; ovf_dst[o] = d_; }
        }

        // src-binned record (for denom)
        int sb = s >> SSH;
        u32 srec = (u32)s | ((u32)d_ << 16);
        int rs = sbase[sb] + atomicAdd(&sfill[sb], 1);
        if (rs < SCAP) {
            srecs[(size_t)sb * SCAP + rs] = srec;
        } else {
            // rare fallback: contribute to denom directly
            atomicAdd(&denom[s], edge_ex(s1[s], s2[d_]));
        }
    }
}

// ---------------------------------------------------------------------------
// Kernel 2b: denom reduction. One block per src-bucket (256 srcs).
// LDS fp32 accumulation -> single contiguous global write (+= picks up
// any overflow-path atomic contributions from k_bin, which ran earlier).
// ---------------------------------------------------------------------------
__global__ void __launch_bounds__(512)
k_denom(const u32* __restrict__ srecs,
        const int* __restrict__ scnt_g,
        const float* __restrict__ s1,
        const float* __restrict__ s2,
        float* __restrict__ denom,
        int N) {
    __shared__ float acc[256];
    const int b = blockIdx.x;
    const int tid = threadIdx.x;
    if (tid < 256) acc[tid] = 0.f;
    __syncthreads();

    const int total = min(scnt_g[b], SCAP);
    const u32* base = srecs + (size_t)b * SCAP;
    for (int i = tid; i < total; i += 512) {
        u32 r = base[i];
        int s = r & 0xFFFF;
        int d = r >> 16;
        atomicAdd(&acc[s & 255], edge_ex(s1[s], s2[d]));
    }
    __syncthreads();

    if (tid < 256) {
        int g = (b << SSH) + tid;
        if (g < N) denom[g] += acc[tid];
    }
}

// ---------------------------------------------------------------------------
// Kernel 3: one block (1024 thr, 16 waves) per 128-node dst-bucket.
// Stage u32 records, recompute ex (s2 in LDS, s1/denom L2 gathers),
// group by local dst in LDS, aggregate with 4-edges-per-wave float4
// gathers, residual + LN.  g = lane>>4 (edge slot), li = lane&15 (col/4).
// ---------------------------------------------------------------------------
__global__ void __launch_bounds__(1024)
k_bucket_agg(const u32* __restrict__ drecs,
             const int* __restrict__ dcnt_g,
             const float* __restrict__ s1,
             const float* __restrict__ s2,
             const float* __restrict__ denom,
             const float* __restrict__ hW,
             const float* __restrict__ gamma,
             const float* __restrict__ beta,
             const u32* __restrict__ ovf_rec,
             const int* __restrict__ ovf_dst,
             const int* __restrict__ ovf_n_p,
             float* __restrict__ out,
             int N) {
    __shared__ u64 ro[BCAP];          // {att_bits:32 | rec:32}
    __shared__ float s2l[BNODES];
    __shared__ int hh[BNODES], oo[BNODES], cc[BNODES];

    const int b    = blockIdx.x;
    const int tid  = threadIdx.x;
    const int lane = tid & 63;
    const int wid  = tid >> 6;        // 16 waves
    const int g    = lane >> 4;       // edge-slot group 0..3
    const int li   = lane & 15;       // column quad 0..15
    const int node0 = b << BSH;
    const int nn    = min(BNODES, N - node0);
    const int total = min(dcnt_g[b], BCAP);

    if (tid < nn) s2l[tid] = s2[node0 + tid];
    if (tid < BNODES) hh[tid] = 0;
    __syncthreads();

    // ---- stage + compute att ----
    u64 rr[3]; bool valid[3];
    const u32* base = drecs + (size_t)b * BCAP;
    #pragma unroll
    for (int q = 0; q < 3; ++q) {
        int idx = tid + q * 1024;
        valid[q] = idx < total;
        u32 r = valid[q] ? base[idx] : 0u;
        if (valid[q]) {
            int s  = r & 0xFFFF;
            int dl = (r >> 16) & (BNODES - 1);
            float att = edge_ex(s1[s], s2l[dl]) / denom[s];
            rr[q] = ((u64)__float_as_uint(att) << 32) | (u64)r;
            atomicAdd(&hh[dl], 1);
        } else rr[q] = 0;
    }
    __syncthreads();

    // ---- exclusive scan over 128 counters ----
    if (tid < BNODES) oo[tid] = hh[tid];
    __syncthreads();
    for (int off = 1; off < BNODES; off <<= 1) {
        int t = 0;
        if (tid < BNODES && tid >= off) t = oo[tid - off];
        __syncthreads();
        if (tid < BNODES) oo[tid] += t;
        __syncthreads();
    }
    if (tid < BNODES) { int e_ = oo[tid] - hh[tid]; oo[tid] = e_; cc[tid] = e_; }
    __syncthreads();

    // ---- scatter into dst-grouped LDS buffer ----
    #pragma unroll
    for (int q = 0; q < 3; ++q) if (valid[q])
        ro[atomicAdd(&cc[((u32)rr[q] >> 16) & (BNODES - 1)], 1)] = rr[q];
    __syncthreads();

    int ovn = *ovf_n_p;
    if (ovn > OVFCAP) ovn = OVFCAP;

    // ---- aggregate + residual + LayerNorm; wave owns nodes wid*8..wid*8+7 ----
    #pragma unroll
    for (int k = 0; k < 8; ++k) {
        int nl = (wid << 3) + k;
        if (nl >= nn) break;
        int beg = oo[nl], end = cc[nl];

        float ax = 0.f, ay = 0.f, az = 0.f, aw = 0.f;
        for (int p = beg; p < end; p += 4) {
            int idx = p + g;
            float att = 0.f; int s = 0;
            if (idx < end) {
                u64 r2 = ro[idx];
                s = (u32)r2 & 0xFFFF;
                att = __uint_as_float((u32)(r2 >> 32));
            }
            const float4 v = *(const float4*)(hW + (size_t)s * D + li * 4);
            ax = fmaf(att, v.x, ax); ay = fmaf(att, v.y, ay);
            az = fmaf(att, v.z, az); aw = fmaf(att, v.w, aw);
        }

        // overflow safety path (normally ovn == 0); add on group 0 only
        for (int r = 0; r < ovn; ++r) {
            if (ovf_dst[r] != node0 + nl) continue;
            if (g == 0) {
                u32 r2 = ovf_rec[r];
                int s = r2 & 0xFFFF;
                float att = edge_ex(s1[s], s2l[nl]) / denom[s];
                const float4 v = *(const float4*)(hW + (size_t)s * D + li * 4);
                ax = fmaf(att, v.x, ax); ay = fmaf(att, v.y, ay);
                az = fmaf(att, v.z, az); aw = fmaf(att, v.w, aw);
            }
        }

        // reduce across the 4 edge-slot groups
        ax += __shfl_xor(ax, 16, 64); ax += __shfl_xor(ax, 32, 64);
        ay += __shfl_xor(ay, 16, 64); ay += __shfl_xor(ay, 32, 64);
        az += __shfl_xor(az, 16, 64); az += __shfl_xor(az, 32, 64);
        aw += __shfl_xor(aw, 16, 64); aw += __shfl_xor(aw, 32, 64);

        // residual
        const float4 hv = *(const float4*)(hW + (size_t)(node0 + nl) * D + li * 4);
        float x0 = hv.x + ax, x1 = hv.y + ay, x2 = hv.z + az, x3 = hv.w + aw;

        // LayerNorm over 64 cols
        float sm = x0 + x1 + x2 + x3;
        sm += __shfl_xor(sm, 1, 64); sm += __shfl_xor(sm, 2, 64);
        sm += __shfl_xor(sm, 4, 64); sm += __shfl_xor(sm, 8, 64);
        float mu = sm * (1.f / D);
        float d0 = x0 - mu, d1 = x1 - mu, d2 = x2 - mu, d3 = x3 - mu;
        float vv = d0 * d0 + d1 * d1 + d2 * d2 + d3 * d3;
        vv += __shfl_xor(vv, 1, 64); vv += __shfl_xor(vv, 2, 64);
        vv += __shfl_xor(vv, 4, 64); vv += __shfl_xor(vv, 8, 64);
        float inv = rsqrtf(vv * (1.f / D) + LN_EPS);

        if (g == 0) {
            const float4 gm = *(const float4*)(gamma + li * 4);
            const float4 bt = *(const float4*)(beta + li * 4);
            float4 o;
            o.x = d0 * inv * gm.x + bt.x;
            o.y = d1 * inv * gm.y + bt.y;
            o.z = d2 * inv * gm.z + bt.z;
            o.w = d3 * inv * gm.w + bt.w;
            *(float4*)(out + (size_t)(node0 + nl) * D + li * 4) = o;
        }
    }
}

// ---------------------------------------------------------------------------
static inline size_t align256(size_t x) { return (x + 255) & ~size_t(255); }

extern "C" void kernel_launch(void* const* d_in, const int* in_sizes, int n_in,
                              void* d_out, int out_size, void* d_ws, size_t ws_size,
                              hipStream_t stream) {
    const float* h    = (const float*)d_in[0];
    const int*   ei   = (const int*)d_in[1];
    const float* W    = (const float*)d_in[2];
    const float* a    = (const float*)d_in[3];
    const float* lng  = (const float*)d_in[4];
    const float* lnb  = (const float*)d_in[5];
    float* out = (float*)d_out;

    const int N = in_sizes[0] / D;
    const int E = in_sizes[1] / 2;
    const int* src = ei;        // edge_index[0]
    const int* dst = ei + E;    // edge_index[1]
    const int nb  = (N + BNODES - 1) >> BSH;   // dst-buckets
    const int nsb = (N + 255) >> SSH;          // src-buckets

    // workspace layout
    char* ws = (char*)d_ws;
    size_t off = 0;
    float* hW      = (float*)(ws + off); off += align256(sizeof(float) * (size_t)N * D);
    float* s1      = (float*)(ws + off); off += align256(sizeof(float) * (size_t)N);
    float* s2      = (float*)(ws + off); off += align256(sizeof(float) * (size_t)N);
    u32*   drecs   = (u32*)  (ws + off); off += align256(sizeof(u32) * (size_t)nb * BCAP);
    u32*   srecs   = (u32*)  (ws + off); off += align256(sizeof(u32) * (size_t)nsb * SCAP);
    u32*   ovf_rec = (u32*)  (ws + off); off += align256(sizeof(u32) * (size_t)OVFCAP);
    int*   ovf_dst = (int*)  (ws + off); off += align256(sizeof(int) * (size_t)OVFCAP);
    // zero-initialized tail: denom, dcnt_g, scnt_g, ovf_n (one memset)
    size_t zero_off = off;
    float* denom   = (float*)(ws + off); off += align256(sizeof(float) * (size_t)N);
    int*   dcnt_g  = (int*)  (ws + off); off += align256(sizeof(int) * (size_t)NBMAX);
    int*   scnt_g  = (int*)  (ws + off); off += align256(sizeof(int) * (size_t)NSBMAX);
    int*   ovf_n   = (int*)  (ws + off); off += align256(sizeof(int));
    size_t zero_bytes = off - zero_off;

    hipMemsetAsync(ws + zero_off, 0, zero_bytes, stream);

    // K1: hW + attention scores
    k_hw_scores<<<dim3(1024), dim3(256), 0, stream>>>(h, W, a, hW, s1, s2, N);

    // K2: dual binning (4096 edges/block), no fp atomics
    k_bin<<<dim3((E + 4095) / 4096), dim3(1024), 0, stream>>>(
        src, dst, s1, s2, denom, dcnt_g, drecs, scnt_g, srecs,
        ovf_rec, ovf_dst, ovf_n, E, nb, nsb);

    // K2b: denom reduction per src-bucket
    k_denom<<<dim3(nsb), dim3(512), 0, stream>>>(srecs, scnt_g, s1, s2, denom, N);

    // K3: fused bucket sort + aggregate + residual + LayerNorm
    k_bucket_agg<<<dim3(nb), dim3(1024), 0, stream>>>(
        drecs, dcnt_g, s1, s2, denom, hW, lng, lnb,
        ovf_rec, ovf_dst, ovf_n, out, N);
}